// Round 9
// baseline (329.882 us; speedup 1.0000x reference)
//
#include <hip/hip_runtime.h>

#define N_NODES 16000
#define N_EDGES 128000
#define GATD 768
#define NODED 32
#define EDGED 16
#define METAIN 800
#define METAD 128
#define YCOLS 384   // [y1 (128) | y2 (128) | yself (128)]

typedef short s16x8 __attribute__((ext_vector_type(8)));
typedef float f32x4v __attribute__((ext_vector_type(4)));

__device__ __forceinline__ unsigned short f2bf(float f){
    unsigned u = __float_as_uint(f);
    return (unsigned short)((u + 0x7fffu + ((u >> 16) & 1u)) >> 16);
}
__device__ __forceinline__ float us2f(unsigned short u){ return __uint_as_float(((unsigned)u)<<16); }

__device__ __forceinline__ void gload16(const void* g, void* l){
    __builtin_amdgcn_global_load_lds((const __attribute__((address_space(1))) void*)g,
                                     (__attribute__((address_space(3))) void*)l, 16, 0, 0);
}

// ---------------- bf16 conversion pre-pass ----------------

__global__ __launch_bounds__(256) void conv_bf16_kernel(const float* __restrict__ in,
                                                        unsigned short* __restrict__ out, int n8){
    int i = blockIdx.x*256 + threadIdx.x;
    if (i >= n8) return;
    const float4* p = reinterpret_cast<const float4*>(in) + (size_t)i*2;
    float4 a = p[0], b = p[1];
    union { unsigned short u[8]; s16x8 v; } o;
    o.u[0]=f2bf(a.x); o.u[1]=f2bf(a.y); o.u[2]=f2bf(a.z); o.u[3]=f2bf(a.w);
    o.u[4]=f2bf(b.x); o.u[5]=f2bf(b.y); o.u[6]=f2bf(b.z); o.u[7]=f2bf(b.w);
    reinterpret_cast<s16x8*>(out)[i] = o.v;
}

// ---------------- merged weight pack ----------------
// blocks 0..143    : LDS-tiled transpose W_gat (768x768 f32) -> WgT (bf16, [c][k])
// blocks 144..1343 : WcatT[c][k] (384x800 bf16) from W_nbr/W_self
// block  1344      : W16 = W_edge @ W3 (16x128 f32), bb[c] = b_edge @ W3
__global__ __launch_bounds__(256) void pack_all_kernel(const float* __restrict__ W_gat,
                                                       const float* __restrict__ W_nbr,
                                                       const float* __restrict__ W_self,
                                                       const float* __restrict__ W_edge,
                                                       const float* __restrict__ b_edge,
                                                       unsigned short* __restrict__ WgT,
                                                       unsigned short* __restrict__ WcatT,
                                                       float* __restrict__ W16g,
                                                       float* __restrict__ bbg){
    int bid = blockIdx.x, tid = threadIdx.x;
    if (bid < 144){
        __shared__ float t[64][65];
        int bi = bid / 12, bj = bid % 12;
        int r16 = tid >> 4, c4 = (tid & 15) * 4;
        #pragma unroll
        for (int it = 0; it < 4; ++it){
            int row = it*16 + r16;
            float4 v = *reinterpret_cast<const float4*>(W_gat + (size_t)(bi*64+row)*GATD + bj*64 + c4);
            t[row][c4+0]=v.x; t[row][c4+1]=v.y; t[row][c4+2]=v.z; t[row][c4+3]=v.w;
        }
        __syncthreads();
        #pragma unroll
        for (int it = 0; it < 4; ++it){
            int row = it*16 + r16;   // output row = original column
            ushort4 o;
            o.x = f2bf(t[c4+0][row]); o.y = f2bf(t[c4+1][row]);
            o.z = f2bf(t[c4+2][row]); o.w = f2bf(t[c4+3][row]);
            *reinterpret_cast<ushort4*>(WgT + (size_t)(bj*64+row)*GATD + bi*64 + c4) = o;
        }
    } else if (bid < 1344){
        int idx = (bid-144)*256 + tid;               // < 384*800
        int c = idx / METAIN, k = idx % METAIN;
        float v;
        if (c < 128)      v = W_nbr[(size_t)k*METAD + c];
        else if (c < 256) v = W_nbr[(size_t)(800+k)*METAD + (c-128)];
        else              v = W_self[(size_t)k*METAD + (c-256)];
        WcatT[idx] = f2bf(v);
    } else {
        int c = tid;
        if (c < 128){
            float w3[16];
            #pragma unroll
            for (int k = 0; k < 16; ++k) w3[k] = W_nbr[(size_t)(1600+k)*METAD + c];
            #pragma unroll
            for (int j = 0; j < 16; ++j){
                float s = 0.f;
                #pragma unroll
                for (int k = 0; k < 16; ++k) s += W_edge[j*16+k] * w3[k];
                W16g[j*128 + c] = s;
            }
            float bb = 0.f;
            #pragma unroll
            for (int k = 0; k < 16; ++k) bb += b_edge[k] * w3[k];
            bbg[c] = bb;
        }
    }
}

// nf -> x_bf[:, 768:800] (bf16)
__global__ __launch_bounds__(256) void nf_kernel(const float* __restrict__ node_feature,
                                                 const float* __restrict__ W_node,
                                                 const float* __restrict__ b_node,
                                                 unsigned short* __restrict__ x_bf){
    __shared__ float Wn[1024];
    __shared__ float bn[32];
    int tid = threadIdx.x;
    for (int i = tid; i < 1024; i += 256) Wn[i] = W_node[i];
    if (tid < 32) bn[tid] = b_node[tid];
    __syncthreads();
    int idx = blockIdx.x*256 + tid;                  // < N*32
    int n = idx >> 5, j = idx & 31;
    const float* row = node_feature + (size_t)n*NODED;
    float s = bn[j];
    #pragma unroll
    for (int k = 0; k < 32; ++k) s += row[k] * Wn[k*32 + j];
    x_bf[(size_t)n*METAIN + GATD + j] = f2bf(s);
}

// ---------------- CSR build ----------------

__global__ __launch_bounds__(256) void deg_kernel(const int* __restrict__ dst, int* __restrict__ deg){
    int e = blockIdx.x*256 + threadIdx.x;
    atomicAdd(&deg[dst[e]], 1);
}

__global__ __launch_bounds__(1024) void scan_kernel(const int* __restrict__ deg,
                                                    int* __restrict__ rowstart,
                                                    int* __restrict__ cursor){
    __shared__ int part[1024];
    int t = threadIdx.x;
    int base = t * 16;
    int local[16];
    int s = 0;
    #pragma unroll
    for (int k = 0; k < 16; ++k){
        int idx = base + k;
        int v = (idx < N_NODES) ? deg[idx] : 0;
        local[k] = s; s += v;
    }
    part[t] = s;
    __syncthreads();
    for (int off = 1; off < 1024; off <<= 1){
        int v = 0;
        if (t >= off) v = part[t-off];
        __syncthreads();
        if (t >= off) part[t] += v;
        __syncthreads();
    }
    int excl = (t == 0) ? 0 : part[t-1];
    #pragma unroll
    for (int k = 0; k < 16; ++k){
        int idx = base + k;
        if (idx < N_NODES){ int rs = excl + local[k]; rowstart[idx] = rs; cursor[idx] = rs; }
    }
    if (t == 1023) rowstart[N_NODES] = part[1023];
}

__global__ __launch_bounds__(256) void csr_kernel(const int* __restrict__ dst,
                                                  int* __restrict__ cursor,
                                                  int* __restrict__ csr){
    int e = blockIdx.x*256 + threadIdx.x;
    int p = atomicAdd(&cursor[dst[e]], 1);
    csr[p] = e;
}

// ---------------- MFMA bf16 GEMM: C = A[M][K] @ Bt[Ncols][K]^T ----------------
// Tile 128(M) x 64(N), BK=64 (two 32-K panels), 256 threads = 4 waves (2x2),
// each wave 64x32 = 4x2 frags of 16x16x32. Grid: blockIdx.x = row block (fastest),
// blockIdx.y = col block. 24 KB LDS -> up to 6 blocks/CU; h-grid 1500 blocks.
// LDS: As = [2 panels][128 rows][32 elems]; Bs = [2 panels][64 rows][32 elems].
// DOTS : epilogue per-row dot with att_src/att_dst from f32 acc, atomicAdd.
// BFOUT: C written as bf16.

template<bool DOTS, bool BFOUT>
__global__ __launch_bounds__(256) void mfma_gemm_kernel(const unsigned short* __restrict__ A,
                                                        const unsigned short* __restrict__ Bt,
                                                        float* __restrict__ Cf,
                                                        unsigned short* __restrict__ Cb,
                                                        const float* __restrict__ att_src,
                                                        const float* __restrict__ att_dst,
                                                        float* __restrict__ a_srcO,
                                                        float* __restrict__ a_dstO,
                                                        int Ncols, int K){
    __shared__ __align__(16) unsigned short As[2*128*32];   // 16 KB
    __shared__ __align__(16) unsigned short Bs[2*64*32];    // 8 KB
    int tid = threadIdx.x;
    int wave = tid >> 6, lane = tid & 63;
    int rowBase = blockIdx.x * 128, colBase = blockIdx.y * 64;
    int r0 = (wave>>1)*64, c0 = (wave&1)*32;
    int rl = lane & 15, kg = lane >> 4;

    // staging maps (chunk = 16B = 8 elems). A: 1024 chunks, B: 512 chunks.
    // chunk c -> panel p, row, quarter q ; LDS byte = c*16 (linear) ;
    // global elem off = row*K + p*32 + q*8
    int cA0 = tid;                                   // + i*256, i=0..3
    int cB0 = tid;                                   // + i*256, i=0..1

    f32x4v acc[4][2] = {};
    for (int k0 = 0; k0 < K; k0 += 64){
        int rem = K - k0; if (rem > 64) rem = 64;    // 64 or (y tail) 32
        int nA = (rem >> 5) * 512;                   // valid A chunks
        int nB = (rem >> 5) * 256;                   // valid B chunks
        __syncthreads();                             // previous iter's LDS reads done
        #pragma unroll
        for (int i = 0; i < 4; ++i){
            int c = cA0 + i*256;
            if (c < nA){
                int p = c >> 9, rr = (c >> 2) & 127, q = c & 3;
                gload16(A + (size_t)(rowBase + rr)*K + k0 + p*32 + q*8,
                        (char*)As + c*16);
            }
        }
        #pragma unroll
        for (int i = 0; i < 2; ++i){
            int c = cB0 + i*256;
            if (c < nB){
                int p = c >> 8, rr = (c >> 2) & 63, q = c & 3;
                gload16(Bt + (size_t)(colBase + rr)*K + k0 + p*32 + q*8,
                        (char*)Bs + c*16);
            }
        }
        __syncthreads();                             // staging complete
        for (int ks = 0; ks*32 < rem; ++ks){
            s16x8 af[4], bfr[2];
            #pragma unroll
            for (int mi = 0; mi < 4; ++mi)
                af[mi] = *reinterpret_cast<const s16x8*>(&As[ks*4096 + (r0 + mi*16 + rl)*32 + kg*8]);
            #pragma unroll
            for (int ni = 0; ni < 2; ++ni)
                bfr[ni] = *reinterpret_cast<const s16x8*>(&Bs[ks*2048 + (c0 + ni*16 + rl)*32 + kg*8]);
            #pragma unroll
            for (int mi = 0; mi < 4; ++mi)
                #pragma unroll
                for (int ni = 0; ni < 2; ++ni)
                    acc[mi][ni] = __builtin_amdgcn_mfma_f32_16x16x32_bf16(af[mi], bfr[ni], acc[mi][ni], 0, 0, 0);
        }
    }
    int orow = rowBase + r0 + kg*4;
    int ocol = colBase + c0 + rl;
    #pragma unroll
    for (int mi = 0; mi < 4; ++mi)
        #pragma unroll
        for (int ni = 0; ni < 2; ++ni){
            #pragma unroll
            for (int j = 0; j < 4; ++j){
                size_t idx = (size_t)(orow + mi*16 + j)*Ncols + ocol + ni*16;
                if constexpr (BFOUT) Cb[idx] = f2bf(acc[mi][ni][j]);
                else                 Cf[idx] = acc[mi][ni][j];
            }
        }
    if constexpr (DOTS){
        float as_c[2], ad_c[2];
        #pragma unroll
        for (int ni = 0; ni < 2; ++ni){
            int col = colBase + c0 + ni*16 + rl;
            as_c[ni] = att_src[col];
            ad_c[ni] = att_dst[col];
        }
        #pragma unroll
        for (int mi = 0; mi < 4; ++mi)
            #pragma unroll
            for (int j = 0; j < 4; ++j){
                float ps = 0.f, pd = 0.f;
                #pragma unroll
                for (int ni = 0; ni < 2; ++ni){
                    float v = acc[mi][ni][j];
                    ps += v * as_c[ni];
                    pd += v * ad_c[ni];
                }
                #pragma unroll
                for (int off = 8; off; off >>= 1){
                    ps += __shfl_xor(ps, off);
                    pd += __shfl_xor(pd, off);
                }
                if (rl == 0){
                    int r = rowBase + r0 + mi*16 + kg*4 + j;
                    atomicAdd(&a_srcO[r], ps);
                    atomicAdd(&a_dstO[r], pd);
                }
            }
    }
}

// ---------------- GAT aggregate: wave per node, fused edge-softmax ----------------
// (max-subtraction skipped: |alpha| << 1 so exp is safe; mathematically identical)

__global__ __launch_bounds__(256) void gat_gather_kernel(const unsigned short* __restrict__ h_bf,
                                                         const float* __restrict__ a_src,
                                                         const float* __restrict__ a_dst,
                                                         const float* __restrict__ b_gat,
                                                         const int* __restrict__ src,
                                                         const int* __restrict__ rowstart,
                                                         const int* __restrict__ csr,
                                                         unsigned short* __restrict__ x_bf){
    int wv = threadIdx.x >> 6, lane = threadIdx.x & 63;
    int i = blockIdx.x*4 + wv;
    float adi = a_dst[i];
    float al = a_src[i] + adi;
    al = al > 0.f ? al : 0.2f*al;
    float ex_self = expf(al);
    const unsigned short* hi = h_bf + (size_t)i*GATD;
    float acc[12];
    #pragma unroll
    for (int c = 0; c < 3; ++c){
        ushort4 v = *reinterpret_cast<const ushort4*>(hi + c*256 + lane*4);
        acc[c*4+0] = ex_self*us2f(v.x); acc[c*4+1] = ex_self*us2f(v.y);
        acc[c*4+2] = ex_self*us2f(v.z); acc[c*4+3] = ex_self*us2f(v.w);
    }
    float dsum = ex_self;
    int rs = rowstart[i], re = rowstart[i+1];
    for (int p = rs; p < re; p += 64){
        int cnt = min(64, re - p);
        int sv = 0; float ev = 0.f;
        if (lane < cnt){
            int e = csr[p+lane];
            sv = src[e];
            float a = a_src[sv] + adi;
            a = a > 0.f ? a : 0.2f*a;
            ev = expf(a);
        }
        for (int j = 0; j < cnt; ++j){
            int   ss = __shfl(sv, j);
            float ww = __shfl(ev, j);
            dsum += ww;
            const unsigned short* hs = h_bf + (size_t)ss*GATD;
            #pragma unroll
            for (int c = 0; c < 3; ++c){
                ushort4 v = *reinterpret_cast<const ushort4*>(hs + c*256 + lane*4);
                acc[c*4+0] += ww*us2f(v.x); acc[c*4+1] += ww*us2f(v.y);
                acc[c*4+2] += ww*us2f(v.z); acc[c*4+3] += ww*us2f(v.w);
            }
        }
    }
    float inv = 1.f / dsum;
    unsigned short* xr = x_bf + (size_t)i*METAIN;
    #pragma unroll
    for (int c = 0; c < 3; ++c){
        float4 bg = *reinterpret_cast<const float4*>(b_gat + c*256 + lane*4);
        ushort4 o;
        o.x = f2bf(acc[c*4+0]*inv + bg.x); o.y = f2bf(acc[c*4+1]*inv + bg.y);
        o.z = f2bf(acc[c*4+2]*inv + bg.z); o.w = f2bf(acc[c*4+3]*inv + bg.w);
        *reinterpret_cast<ushort4*>(xr + c*256 + lane*4) = o;
    }
}

// ---------------- final aggregation (ez folded: ez = edge_attr@W16 + bb) ----------------

__global__ __launch_bounds__(128) void out_gather_kernel(const float* __restrict__ y,
                                                         const float* __restrict__ edge_attr,
                                                         const float* __restrict__ W16g,
                                                         const float* __restrict__ bbg,
                                                         const float* __restrict__ b_nbr,
                                                         const float* __restrict__ b_self,
                                                         const int* __restrict__ src,
                                                         const int* __restrict__ rowstart,
                                                         const int* __restrict__ csr,
                                                         float* __restrict__ out){
    __shared__ float W3[16*128];
    __shared__ int   s_src[32];
    __shared__ int   s_eid[32];
    __shared__ float s_ea[32*16];
    int i = blockIdx.x, c = threadIdx.x;
    #pragma unroll
    for (int k = 0; k < 16; ++k) W3[k*128 + c] = W16g[k*128 + c];
    int rs = rowstart[i], re = rowstart[i+1];
    int deg = re - rs;
    float acc = 0.f;
    for (int p = rs; p < re; p += 32){
        int cnt = min(32, re - p);
        __syncthreads();
        if (c < cnt){ int e = csr[p+c]; s_eid[c] = e; s_src[c] = src[e]; }
        __syncthreads();
        for (int idx = c; idx < cnt*16; idx += 128){
            int j = idx >> 4, k = idx & 15;
            s_ea[idx] = edge_attr[(size_t)s_eid[j]*EDGED + k];
        }
        __syncthreads();
        for (int j = 0; j < cnt; ++j){
            acc += y[(size_t)s_src[j]*YCOLS + 128 + c];
            float ez = 0.f;
            #pragma unroll
            for (int k = 0; k < 16; ++k) ez += s_ea[j*16 + k] * W3[k*128 + c];
            acc += ez;
        }
    }
    float y1 = y[(size_t)i*YCOLS + c];
    float ys = y[(size_t)i*YCOLS + 256 + c];
    float outv = (float)deg * (y1 + b_nbr[c] + bbg[c]) + acc + ys + b_self[c];
    out[(size_t)i*METAD + c] = outv;
}

// ---------------- launch ----------------

extern "C" void kernel_launch(void* const* d_in, const int* in_sizes, int n_in,
                              void* d_out, int out_size, void* d_ws, size_t ws_size,
                              hipStream_t stream){
    const float* node_feature    = (const float*)d_in[0];
    const float* edge_attr       = (const float*)d_in[1];
    const float* message_feature = (const float*)d_in[2];
    const int*   edge_index      = (const int*)d_in[3];
    const float* W_node = (const float*)d_in[4];
    const float* b_node = (const float*)d_in[5];
    const float* W_edge = (const float*)d_in[6];
    const float* b_edge = (const float*)d_in[7];
    const float* W_gat  = (const float*)d_in[8];
    const float* att_src= (const float*)d_in[9];
    const float* att_dst= (const float*)d_in[10];
    const float* b_gat  = (const float*)d_in[11];
    const float* W_nbr  = (const float*)d_in[12];
    const float* b_nbr  = (const float*)d_in[13];
    const float* W_self = (const float*)d_in[14];
    const float* b_self = (const float*)d_in[15];
    float* out = (float*)d_out;

    char* wsb = (char*)d_ws;
    size_t off = 0;
    auto walloc = [&](size_t bytes)->void*{
        void* p = wsb + off;
        off = (off + bytes + 511) & ~(size_t)511;
        return p;
    };
    unsigned short* h_bf  = (unsigned short*)walloc((size_t)N_NODES*GATD*2);   // 24.6 MB
    float* y              = (float*)walloc((size_t)N_NODES*YCOLS*4);           // 24.6 MB
    unsigned short* A_bf  = (unsigned short*)walloc((size_t)N_NODES*GATD*2);   // 24.6 MB
    unsigned short* x_bf  = (unsigned short*)walloc((size_t)N_NODES*METAIN*2); // 25.6 MB
    unsigned short* WgT   = (unsigned short*)walloc((size_t)GATD*GATD*2);      // 1.2 MB
    unsigned short* WcatT = (unsigned short*)walloc((size_t)YCOLS*METAIN*2);   // 0.6 MB
    float* W16g   = (float*)walloc(16*128*4);
    float* bbg    = (float*)walloc(128*4);
    float* zbase  = (float*)walloc((size_t)3*N_NODES*4);   // [a_src | a_dst | deg] contiguous
    float* a_src  = zbase;
    float* a_dst  = zbase + N_NODES;
    int*   deg    = (int*)(zbase + 2*N_NODES);
    int* rowstart = (int*)walloc((size_t)(N_NODES+1)*4);
    int* cursor   = (int*)walloc((size_t)N_NODES*4);
    int* csr      = (int*)walloc((size_t)N_EDGES*4);

    const int* src = edge_index;
    const int* dst = edge_index + N_EDGES;

    hipMemsetAsync(zbase, 0, (size_t)3*N_NODES*4, stream);

    conv_bf16_kernel<<<(N_NODES*GATD/8 + 255)/256, 256, 0, stream>>>(message_feature, A_bf, N_NODES*GATD/8);
    pack_all_kernel<<<1345, 256, 0, stream>>>(W_gat, W_nbr, W_self, W_edge, b_edge,
                                              WgT, WcatT, W16g, bbg);
    nf_kernel<<<(N_NODES*NODED)/256, 256, 0, stream>>>(node_feature, W_node, b_node, x_bf);
    deg_kernel<<<N_EDGES/256, 256, 0, stream>>>(dst, deg);
    scan_kernel<<<1, 1024, 0, stream>>>((const int*)deg, rowstart, cursor);
    csr_kernel<<<N_EDGES/256, 256, 0, stream>>>(dst, cursor, csr);

    // h_bf = bf16(mf @ W_gat), fused attention dots (a_src/a_dst via atomics)
    mfma_gemm_kernel<true,true><<<dim3(N_NODES/128, GATD/64), 256, 0, stream>>>(
        A_bf, WgT, nullptr, h_bf, att_src, att_dst, a_src, a_dst, GATD, GATD);

    gat_gather_kernel<<<N_NODES/4, 256, 0, stream>>>(h_bf, a_src, a_dst, b_gat, src, rowstart, csr, x_bf);

    // y = x @ Wcat   [16000 x 384], K=800 (12x64 + 32 tail)
    mfma_gemm_kernel<false,false><<<dim3(N_NODES/128, YCOLS/64), 256, 0, stream>>>(
        x_bf, WcatT, y, nullptr, nullptr, nullptr, nullptr, nullptr, YCOLS, METAIN);

    out_gather_kernel<<<N_NODES, 128, 0, stream>>>(y, edge_attr, W16g, bbg, b_nbr, b_self,
                                                   src, rowstart, csr, out);
}